// Round 10
// baseline (64.366 us; speedup 1.0000x reference)
//
#include <hip/hip_runtime.h>

#define B_ 8
#define P_ 65536
#define G_ 32
#define C_ 2
#define K_ 5
#define T1_ 0.35f
#define T2_ 0.5f
#define ALPHA_ 0.25f
#define BETA_ 0.11f
#define V0_ 0.1f
#define V1_ 0.2f

#define NBLK_ 256                 // blocks per image for kA / kB-part (1 anchor/thread)
#define CH_ 8                     // top-5 chunks per (b,g)
#define CHP_ (P_ / CH_)           // 8192 anchors per chunk

// ws layout (plain-store scratch; every word written each call before any read):
//   [0)      float  best_score[B_*P_]        2 MB
//   +2MB     int    best_idx[B_*P_]          2 MB
//   +4MB     double fl_n_p[2048]; sl_n_p[2048]          32 KB
//   +..      float  cv5[8*32*8*5]; int ci5[8*32*8*5]    80 KB
//   +..      int    histA[256][256]  ([blk][b*32+g])    256 KB
//   +..      int    histC[256][256]                     256 KB

// ---------------- numerics helpers (contract off => deterministic across call sites) ----
struct DecBox { float x1, y1, x2, y2, area; };

__device__ __forceinline__ DecBox decode_box(float4 pr, float4 lc) {
#pragma clang fp contract(off)
    DecBox d;
    float dcx = pr.x + lc.x * V0_ * pr.z;
    float dcy = pr.y + lc.y * V0_ * pr.w;
    float dw = pr.z * expf(lc.z * V1_);
    float dh = pr.w * expf(lc.w * V1_);
    d.x1 = dcx - dw * 0.5f; d.y1 = dcy - dh * 0.5f;
    d.x2 = dcx + dw * 0.5f; d.y2 = dcy + dh * 0.5f;
    d.area = (d.x2 - d.x1) * (d.y2 - d.y1);
    return d;
}

__device__ __forceinline__ float iou_dec(DecBox d, float aa,
                                         float tx1, float ty1, float tx2, float ty2) {
#pragma clang fp contract(off)
    float lx = fmaxf(tx1, d.x1), ly = fmaxf(ty1, d.y1);
    float rx = fminf(tx2, d.x2), ry = fminf(ty2, d.y2);
    float w = fmaxf(rx - lx, 0.f), hh = fmaxf(ry - ly, 0.f);
    float inter = w * hh;
    return inter / (aa + d.area - inter);
}

__device__ __forceinline__ float focal_f(float t, float x, float fiou) {
    float ce = fmaxf(x, 0.f) - x * t + log1pf(expf(-fabsf(x)));
    float a = (t * ALPHA_ + (1.f - t) * (1.f - ALPHA_)) * fiou;
    float pt = (t == 1.0f) ? x : 1.f - x;
    float om = 1.f - pt;
    return a * om * om * ce;  // GAMMA = 2
}

__device__ __forceinline__ float sml1(float p, float t) {
    float x = fabsf(p - t);
    return (x >= BETA_) ? (x - 0.5f * BETA_) : (0.5f * x * x / BETA_);
}

// top-5 by (value desc, index asc) — the stable-argsort order
__device__ __forceinline__ void top5_insert(float v, int i, float lv[5], int li[5]) {
    if ((v > lv[4]) || (v == lv[4] && i < li[4])) {
        lv[4] = v; li[4] = i;
#pragma unroll
        for (int k = 4; k > 0; --k) {
            bool sw = (lv[k] > lv[k - 1]) || (lv[k] == lv[k - 1] && li[k] < li[k - 1]);
            if (sw) {
                float tv = lv[k]; lv[k] = lv[k - 1]; lv[k - 1] = tv;
                int ti = li[k]; li[k] = li[k - 1]; li[k - 1] = ti;
            }
        }
    }
}

// ---------------- kA: best match per anchor; per-block hist (coalesced plain stores) ----
__global__ __launch_bounds__(256) void kA(const float* __restrict__ priors,
                                          const float* __restrict__ targets,
                                          float* __restrict__ best_score,
                                          int* __restrict__ best_idx,
                                          int* __restrict__ histA) {
    int tid = threadIdx.x, blk = blockIdx.x, b = blockIdx.y;
    __shared__ float tr[G_ * 5];
    __shared__ float gA[G_];
    __shared__ int hist[G_];
    if (tid < G_ * 5) tr[tid] = targets[b * G_ * 5 + tid];
    if (tid < G_) hist[tid] = 0;
    __syncthreads();
    if (tid < G_)
        gA[tid] = (tr[tid * 5 + 2] - tr[tid * 5 + 0]) * (tr[tid * 5 + 3] - tr[tid * 5 + 1]);
    __syncthreads();
    int p = blk * 256 + tid;
    float4 pr = ((const float4*)priors)[p];
    float px1 = pr.x - pr.z * 0.5f, py1 = pr.y - pr.w * 0.5f;
    float px2 = pr.x + pr.z * 0.5f, py2 = pr.y + pr.w * 0.5f;
    float parea = (px2 - px1) * (py2 - py1);
    float best = -INFINITY;
    int bix = 0;
    for (int g = 0; g < G_; ++g) {
        float lx = fmaxf(tr[g * 5 + 0], px1), ly = fmaxf(tr[g * 5 + 1], py1);
        float rx = fminf(tr[g * 5 + 2], px2), ry = fminf(tr[g * 5 + 3], py2);
        float w = fmaxf(rx - lx, 0.f), hh = fmaxf(ry - ly, 0.f);
        float inter = w * hh;
        float v = inter / (gA[g] + parea - inter);
        if (v > best) { best = v; bix = g; }  // first-max == jnp.argmax
    }
    best_score[b * P_ + p] = best;
    best_idx[b * P_ + p] = bix;
    if (best > T1_) atomicAdd(&hist[bix], 1);  // LDS atomic only
    __syncthreads();
    if (tid < G_) histA[blk * 256 + b * G_ + tid] = hist[tid];
}

// ---------------- kBD: heterogeneous. x<256: kB (losses + histC). x>=256: kD top-5 -----
__global__ __launch_bounds__(256) void kBD(
    const float* __restrict__ loc, const float* __restrict__ conf,
    const float* __restrict__ priors, const float* __restrict__ targets,
    const float* __restrict__ best_score, const int* __restrict__ best_idx,
    const int* __restrict__ histA,
    int* __restrict__ histC,
    double* __restrict__ fl_n_p, double* __restrict__ sl_n_p,
    float* __restrict__ cv5, int* __restrict__ ci5) {
    int tid = threadIdx.x, b = blockIdx.y;
    __shared__ union USm {
        struct {
            float tr[G_ * 5]; float gA[G_];
            int outf[G_]; int hist[G_];
            int iscr[8][G_]; double wred[8];
        } Bp;
        struct { float sv[256 * 5]; int si[256 * 5]; int r4[4]; } Dp;
    } u;

    if (blockIdx.x < NBLK_) {
        // ================= kB part =================
        int blk = blockIdx.x;
        if (tid < G_ * 5) u.Bp.tr[tid] = targets[b * G_ * 5 + tid];
        if (tid < G_) u.Bp.hist[tid] = 0;
        {   // match_cnt partial reduce: group grp sums 32 blk-entries for each g
            int g = tid & 31, grp = tid >> 5;
            int s = 0;
#pragma unroll 8
            for (int j = 0; j < 32; ++j)
                s += histA[(grp * 32 + j) * 256 + b * G_ + g];
            u.Bp.iscr[grp][g] = s;
        }
        __syncthreads();
        if (tid < G_) {
            u.Bp.gA[tid] = (u.Bp.tr[tid * 5 + 2] - u.Bp.tr[tid * 5 + 0]) *
                           (u.Bp.tr[tid * 5 + 3] - u.Bp.tr[tid * 5 + 1]);
            int m = 0;
#pragma unroll
            for (int j = 0; j < 8; ++j) m += u.Bp.iscr[j][tid];
            u.Bp.outf[tid] = (m < K_) ? 1 : 0;
        }
        __syncthreads();

        int p = blk * 256 + tid;
        float4 pr = ((const float4*)priors)[p];
        float4 lc = ((const float4*)loc)[(size_t)b * P_ + p];
        float bs = best_score[b * P_ + p];
        int bi = best_idx[b * P_ + p];
        DecBox d = decode_box(pr, lc);
        bool n_pos = bs > T1_;
        float cmax = -INFINITY, mbest = -INFINITY;
        int mg = 0;
        for (int g = 0; g < G_; ++g) {
            float v = iou_dec(d, u.Bp.gA[g], u.Bp.tr[g * 5], u.Bp.tr[g * 5 + 1],
                              u.Bp.tr[g * 5 + 2], u.Bp.tr[g * 5 + 3]);
            cmax = fmaxf(cmax, v);
            bool kill = u.Bp.outf[g] && (bi == g) && n_pos;
            float v2 = kill ? 0.f : v;
            float m = u.Bp.outf[g] ? v2 : -1.f;
            if (m > mbest) { mbest = m; mg = g; }  // first-max
        }
        if (mbest > T2_) atomicAdd(&u.Bp.hist[mg], 1);  // LDS atomic only
        bool ignore = (cmax > T2_) && (bs < T1_);
        bool neg = !(n_pos || ignore);
        double fl = 0.0, sl = 0.0;
        int lab = (int)u.Bp.tr[bi * 5 + 4];
        float2 cf = ((const float2*)conf)[(size_t)b * P_ + p];
        float cfs[2] = {cf.x, cf.y};
#pragma unroll
        for (int c = 0; c < C_; ++c) {
            if (n_pos) fl += (double)focal_f((c == lab) ? 1.f : 0.f, cfs[c], 1.f);
            else if (neg) fl += (double)focal_f(0.f, cfs[c], 1.f);
        }
        if (n_pos) {
            float tx1 = u.Bp.tr[bi * 5], ty1 = u.Bp.tr[bi * 5 + 1];
            float tx2 = u.Bp.tr[bi * 5 + 2], ty2 = u.Bp.tr[bi * 5 + 3];
            float e0 = ((tx1 + tx2) * 0.5f - pr.x) / (V0_ * pr.z);
            float e1 = ((ty1 + ty2) * 0.5f - pr.y) / (V0_ * pr.w);
            float e2 = logf((tx2 - tx1) / pr.z) / V1_;
            float e3 = logf((ty2 - ty1) / pr.w) / V1_;
            sl = (double)sml1(lc.x, e0) + (double)sml1(lc.y, e1) +
                 (double)sml1(lc.z, e2) + (double)sml1(lc.w, e3);
        }
        int lane = tid & 63, w = tid >> 6;
        for (int off = 32; off > 0; off >>= 1) {
            fl += __shfl_down(fl, off, 64);
            sl += __shfl_down(sl, off, 64);
        }
        if (lane == 0) { u.Bp.wred[w] = fl; u.Bp.wred[4 + w] = sl; }
        __syncthreads();  // wred + hist final
        if (tid == 0)
            fl_n_p[b * NBLK_ + blk] = u.Bp.wred[0] + u.Bp.wred[1] + u.Bp.wred[2] + u.Bp.wred[3];
        if (tid == 1)
            sl_n_p[b * NBLK_ + blk] = u.Bp.wred[4] + u.Bp.wred[5] + u.Bp.wred[6] + u.Bp.wred[7];
        if (tid < G_) histC[blk * 256 + b * G_ + tid] = u.Bp.hist[tid];
    } else {
        // ================= kD part (mc<K filter; cm applied later in kTail) =============
        int t2 = blockIdx.x - NBLK_;
        int tg = t2 >> 3, tch = t2 & (CH_ - 1), tb = b;
        // mc = column sum of histA for row (tb,tg)
        {
            int v = histA[tid * 256 + tb * G_ + tg];
            for (int off = 32; off > 0; off >>= 1) v += __shfl_down(v, off, 64);
            if ((tid & 63) == 0) u.Dp.r4[tid >> 6] = v;
        }
        __syncthreads();
        int mc = u.Dp.r4[0] + u.Dp.r4[1] + u.Dp.r4[2] + u.Dp.r4[3];
        if (mc >= K_) return;  // uniform per block; rows with mc<K but cm==0 are harmless

        const float* tgp = targets + (tb * G_ + tg) * 5;
        float tx1 = tgp[0], ty1 = tgp[1], tx2 = tgp[2], ty2 = tgp[3];
        float aa = (tx2 - tx1) * (ty2 - ty1);
        float lv[5];
        int li[5];
#pragma unroll
        for (int k = 0; k < 5; ++k) { lv[k] = -INFINITY; li[k] = 0x7fffffff; }
        int base = tch * CHP_;
        for (int it = 0; it < CHP_ / 256; ++it) {
            int p = base + it * 256 + tid;
            int pbi = best_idx[tb * P_ + p];
            float pbs = best_score[tb * P_ + p];
            float v2;
            if (pbi == tg && pbs > T1_) v2 = 0.f;  // kill (outface true: mc<K)
            else {
                float4 pr = ((const float4*)priors)[p];
                float4 lc = ((const float4*)loc)[(size_t)tb * P_ + p];
                v2 = iou_dec(decode_box(pr, lc), aa, tx1, ty1, tx2, ty2);
            }
            top5_insert(v2, p, lv, li);
        }
#pragma unroll
        for (int k = 0; k < 5; ++k) { u.Dp.sv[tid * 5 + k] = lv[k]; u.Dp.si[tid * 5 + k] = li[k]; }
        __syncthreads();
        for (int str = 128; str > 0; str >>= 1) {
            if (tid < str) {
                int a = 0, c = 0;
                float ov[5];
                int oi[5];
#pragma unroll
                for (int k = 0; k < 5; ++k) {
                    float va = u.Dp.sv[tid * 5 + a], vb = u.Dp.sv[(tid + str) * 5 + c];
                    int ia = u.Dp.si[tid * 5 + a], ib = u.Dp.si[(tid + str) * 5 + c];
                    bool ta = (va > vb) || (va == vb && ia < ib);
                    ov[k] = ta ? va : vb;
                    oi[k] = ta ? ia : ib;
                    if (ta) a++; else c++;
                }
#pragma unroll
                for (int k = 0; k < 5; ++k) { u.Dp.sv[tid * 5 + k] = ov[k]; u.Dp.si[tid * 5 + k] = oi[k]; }
            }
            __syncthreads();
        }
        if (tid == 0) {
#pragma unroll
            for (int k = 0; k < 5; ++k) {
                cv5[((tb * G_ + tg) * CH_ + tch) * 5 + k] = u.Dp.sv[k];
                ci5[((tb * G_ + tg) * CH_ + tch) * 5 + k] = u.Dp.si[k];
            }
        }
    }
}

// ---------------- kTail: mc/cm column sums, merge top-5s, overrides, finalize -----------
__global__ __launch_bounds__(256) void kTail(
    const float* __restrict__ loc, const float* __restrict__ conf,
    const float* __restrict__ priors, const float* __restrict__ targets,
    const int* __restrict__ histA, const int* __restrict__ histC,
    const double* __restrict__ fl_n_p, const double* __restrict__ sl_n_p,
    const float* __restrict__ cv5, const int* __restrict__ ci5,
    float* __restrict__ out) {
    int t = threadIdx.x, b = t >> 5, g = t & 31;
    __shared__ int selp[256][5];
    __shared__ int nS[256];
    __shared__ double aFlc[B_], aSlc[B_], aFln[B_], aSln[B_];
    __shared__ int aNp[B_], aCs[B_], aNpc[B_];

    // mc/cm: coalesced column sums (at each blk, threads read 256 consecutive ints)
    int mc = 0, cm = 0;
    for (int blk = 0; blk < NBLK_; ++blk) {
        mc += histA[blk * 256 + t];
        cm += histC[blk * 256 + t];
    }
    int n = (mc < K_) ? min(cm, K_ - mc) : 0;
    nS[t] = n;
    float mv[5];
    int mi[5];
#pragma unroll
    for (int k = 0; k < 5; ++k) { mv[k] = -INFINITY; mi[k] = 0x7fffffff; }
    if (n > 0) {
        for (int ch = 0; ch < CH_; ++ch)
#pragma unroll
            for (int k = 0; k < 5; ++k)
                top5_insert(cv5[(t * CH_ + ch) * 5 + k], ci5[(t * CH_ + ch) * 5 + k], mv, mi);
    }
#pragma unroll
    for (int k = 0; k < 5; ++k) selp[t][k] = (k < n) ? mi[k] : -1;
    __syncthreads();

    // override resolution (ascending g: later g wins) + compensation losses
    double flc = 0.0, slc = 0.0;
    int alive = 0;
    float tg0 = targets[t * 5 + 0], tg1 = targets[t * 5 + 1];
    float tg2 = targets[t * 5 + 2], tg3 = targets[t * 5 + 3];
    float labf = targets[t * 5 + 4];
    int labi = (int)labf;
    for (int k = 0; k < n; ++k) {
        int p = mi[k];
        bool dead = false;
        for (int g2 = g + 1; g2 < G_; ++g2) {
            int q = b * G_ + g2;
            int n2 = nS[q];
            for (int k2 = 0; k2 < n2; ++k2)
                if (selp[q][k2] == p) dead = true;
        }
        if (!dead) {
            alive++;
            float4 pr = ((const float4*)priors)[p];
            float4 lc = ((const float4*)loc)[(size_t)b * P_ + p];
            float e0 = ((tg0 + tg2) * 0.5f - pr.x) / (V0_ * pr.z);
            float e1 = ((tg1 + tg3) * 0.5f - pr.y) / (V0_ * pr.w);
            float e2 = logf((tg2 - tg0) / pr.z) / V1_;
            float e3 = logf((tg3 - tg1) / pr.w) / V1_;
            slc += (double)sml1(lc.x, e0) + (double)sml1(lc.y, e1) +
                   (double)sml1(lc.z, e2) + (double)sml1(lc.w, e3);
            float2 cf = ((const float2*)conf)[(size_t)b * P_ + p];
            float cfs[2] = {cf.x, cf.y};
#pragma unroll
            for (int c = 0; c < C_; ++c) {
                float tt = (c == labi) ? labf : 0.f;  // labels[g] * one_hot
                flc += (double)focal_f(tt, cfs[c], mv[k]);
            }
        }
    }

    // per-b reductions within 32-thread subgroups (256 partial slots per image)
    int rmc = mc, rn = n, ra = alive;
    double rf = flc, rs = slc;
    double pf = 0.0, ps = 0.0;
    for (int j = 0; j < 8; ++j) {
        pf += fl_n_p[b * NBLK_ + g * 8 + j];
        ps += sl_n_p[b * NBLK_ + g * 8 + j];
    }
    for (int off = 16; off > 0; off >>= 1) {
        rmc += __shfl_down(rmc, off, 32);
        rn += __shfl_down(rn, off, 32);
        ra += __shfl_down(ra, off, 32);
        rf += __shfl_down(rf, off, 32);
        rs += __shfl_down(rs, off, 32);
        pf += __shfl_down(pf, off, 32);
        ps += __shfl_down(ps, off, 32);
    }
    if (g == 0) {
        aNp[b] = rmc; aCs[b] = rn; aNpc[b] = ra;
        aFlc[b] = rf; aSlc[b] = rs; aFln[b] = pf; aSln[b] = ps;
    }
    __syncthreads();
    if (t == 0) {
        double sll = 0.0, scl = 0.0;
        for (int b2 = 0; b2 < B_; ++b2) {
            double l_loc = 0.0, l_cls = 0.0;
            int npos = aNp[b2];
            if (npos > 0) {
                l_cls += aFln[b2] / (double)npos;
                l_loc += aSln[b2] / (double)npos;
            }
            int csum = aCs[b2];
            if (csum > 0) {
                int npc = (aNpc[b2] > 1) ? aNpc[b2] : 1;
                l_loc += aSlc[b2] / (double)npc;
                l_cls += aFlc[b2] / (double)csum;
            }
            sll += l_loc;
            scl += l_cls;
        }
        out[0] = (float)(sll / B_);
        out[1] = (float)(scl / B_);
    }
}

extern "C" void kernel_launch(void* const* d_in, const int* in_sizes, int n_in,
                              void* d_out, int out_size, void* d_ws, size_t ws_size,
                              hipStream_t stream) {
    (void)in_sizes; (void)n_in; (void)out_size; (void)ws_size;
    const float* loc = (const float*)d_in[0];
    const float* conf = (const float*)d_in[1];
    const float* priors = (const float*)d_in[2];
    const float* targets = (const float*)d_in[3];
    float* out = (float*)d_out;
    char* ws = (char*)d_ws;

    float* best_score = (float*)ws;                               // 2 MB
    int* best_idx = (int*)(ws + (size_t)2 * 1024 * 1024);         // 2 MB
    double* fl_n_p = (double*)(ws + (size_t)4 * 1024 * 1024);     // 2048 doubles
    double* sl_n_p = fl_n_p + B_ * NBLK_;                         // 2048 doubles
    float* cv5 = (float*)(sl_n_p + B_ * NBLK_);                   // 10240 floats
    int* ci5 = (int*)(cv5 + B_ * G_ * CH_ * 5);                   // 10240 ints
    int* histA = ci5 + B_ * G_ * CH_ * 5;                         // 64K ints
    int* histC = histA + NBLK_ * 256;                             // 64K ints

    kA<<<dim3(NBLK_, B_), 256, 0, stream>>>(priors, targets, best_score, best_idx, histA);
    kBD<<<dim3(NBLK_ + G_ * CH_, B_), 256, 0, stream>>>(loc, conf, priors, targets,
                                                        best_score, best_idx, histA,
                                                        histC, fl_n_p, sl_n_p, cv5, ci5);
    kTail<<<1, 256, 0, stream>>>(loc, conf, priors, targets, histA, histC,
                                 fl_n_p, sl_n_p, cv5, ci5, out);
}

// Round 11
// 59.703 us; speedup vs baseline: 1.0781x; 1.0781x over previous
//
#include <hip/hip_runtime.h>

#define B_ 8
#define P_ 65536
#define G_ 32
#define C_ 2
#define K_ 5
#define T1_ 0.35f
#define T2_ 0.5f
#define ALPHA_ 0.25f
#define BETA_ 0.11f
#define V0_ 0.1f
#define V1_ 0.2f

#define ABLK_ 64                  // kA / kB-part blocks per image (4 anchors/thread)
#define APB_ 1024                 // anchors per block

// ws layout (plain-store scratch; every word written each call before any read):
//   [0)      float  best_score[B_*P_]        2 MB
//   +2MB     int    best_idx[B_*P_]          2 MB
//   +4MB     double fl_n_p[512]; sl_n_p[512]            8 KB
//   +..      float  cv5[256*5]; int ci5[256*5]          10 KB
//   +..      int    histA[64][256]; histC[64][256]      128 KB   ([blk][b*32+g])

// ---------------- numerics helpers (contract off => deterministic across call sites) ----
struct DecBox { float x1, y1, x2, y2, area; };

__device__ __forceinline__ DecBox decode_box(float4 pr, float4 lc) {
#pragma clang fp contract(off)
    DecBox d;
    float dcx = pr.x + lc.x * V0_ * pr.z;
    float dcy = pr.y + lc.y * V0_ * pr.w;
    float dw = pr.z * expf(lc.z * V1_);
    float dh = pr.w * expf(lc.w * V1_);
    d.x1 = dcx - dw * 0.5f; d.y1 = dcy - dh * 0.5f;
    d.x2 = dcx + dw * 0.5f; d.y2 = dcy + dh * 0.5f;
    d.area = (d.x2 - d.x1) * (d.y2 - d.y1);
    return d;
}

__device__ __forceinline__ float iou_dec(DecBox d, float aa,
                                         float tx1, float ty1, float tx2, float ty2) {
#pragma clang fp contract(off)
    float lx = fmaxf(tx1, d.x1), ly = fmaxf(ty1, d.y1);
    float rx = fminf(tx2, d.x2), ry = fminf(ty2, d.y2);
    float w = fmaxf(rx - lx, 0.f), hh = fmaxf(ry - ly, 0.f);
    float inter = w * hh;
    return inter / (aa + d.area - inter);
}

__device__ __forceinline__ float focal_f(float t, float x, float fiou) {
    float ce = fmaxf(x, 0.f) - x * t + log1pf(expf(-fabsf(x)));
    float a = (t * ALPHA_ + (1.f - t) * (1.f - ALPHA_)) * fiou;
    float pt = (t == 1.0f) ? x : 1.f - x;
    float om = 1.f - pt;
    return a * om * om * ce;  // GAMMA = 2
}

__device__ __forceinline__ float sml1(float p, float t) {
    float x = fabsf(p - t);
    return (x >= BETA_) ? (x - 0.5f * BETA_) : (0.5f * x * x / BETA_);
}

// top-5 by (value desc, index asc) — the stable-argsort order
__device__ __forceinline__ void top5_insert(float v, int i, float lv[5], int li[5]) {
    if ((v > lv[4]) || (v == lv[4] && i < li[4])) {
        lv[4] = v; li[4] = i;
#pragma unroll
        for (int k = 4; k > 0; --k) {
            bool sw = (lv[k] > lv[k - 1]) || (lv[k] == lv[k - 1] && li[k] < li[k - 1]);
            if (sw) {
                float tv = lv[k]; lv[k] = lv[k - 1]; lv[k - 1] = tv;
                int ti = li[k]; li[k] = li[k - 1]; li[k - 1] = ti;
            }
        }
    }
}

// ---------------- kA: best match per anchor; per-block hist (coalesced plain stores) ----
__global__ __launch_bounds__(256) void kA(const float* __restrict__ priors,
                                          const float* __restrict__ targets,
                                          float* __restrict__ best_score,
                                          int* __restrict__ best_idx,
                                          int* __restrict__ histA) {
    int tid = threadIdx.x, blk = blockIdx.x, b = blockIdx.y;
    __shared__ float tr[G_ * 5];
    __shared__ float gA[G_];
    __shared__ int hist[G_];
    if (tid < G_ * 5) tr[tid] = targets[b * G_ * 5 + tid];
    if (tid < G_) hist[tid] = 0;
    __syncthreads();
    if (tid < G_)
        gA[tid] = (tr[tid * 5 + 2] - tr[tid * 5 + 0]) * (tr[tid * 5 + 3] - tr[tid * 5 + 1]);
    __syncthreads();
#pragma unroll
    for (int j = 0; j < 4; ++j) {
        int p = blk * APB_ + j * 256 + tid;
        float4 pr = ((const float4*)priors)[p];
        float px1 = pr.x - pr.z * 0.5f, py1 = pr.y - pr.w * 0.5f;
        float px2 = pr.x + pr.z * 0.5f, py2 = pr.y + pr.w * 0.5f;
        float parea = (px2 - px1) * (py2 - py1);
        float best = -INFINITY;
        int bix = 0;
        for (int g = 0; g < G_; ++g) {
            float lx = fmaxf(tr[g * 5 + 0], px1), ly = fmaxf(tr[g * 5 + 1], py1);
            float rx = fminf(tr[g * 5 + 2], px2), ry = fminf(tr[g * 5 + 3], py2);
            float w = fmaxf(rx - lx, 0.f), hh = fmaxf(ry - ly, 0.f);
            float inter = w * hh;
            float v = inter / (gA[g] + parea - inter);
            if (v > best) { best = v; bix = g; }  // first-max == jnp.argmax
        }
        best_score[b * P_ + p] = best;
        best_idx[b * P_ + p] = bix;
        if (best > T1_) atomicAdd(&hist[bix], 1);  // LDS atomic only
    }
    __syncthreads();
    if (tid < G_) histA[blk * 256 + b * G_ + tid] = hist[tid];
}

// ---------------- kBD: heterogeneous. x<64: kB (losses + histC). x>=64: kD top-5 -------
__global__ __launch_bounds__(256) void kBD(
    const float* __restrict__ loc, const float* __restrict__ conf,
    const float* __restrict__ priors, const float* __restrict__ targets,
    const float* __restrict__ best_score, const int* __restrict__ best_idx,
    const int* __restrict__ histA,
    int* __restrict__ histC,
    double* __restrict__ fl_n_p, double* __restrict__ sl_n_p,
    float* __restrict__ cv5, int* __restrict__ ci5) {
    int tid = threadIdx.x, b = blockIdx.y;
    __shared__ union USm {
        struct {
            float tr[G_ * 5]; float gA[G_];
            int outf[G_]; int hist[G_]; double wred[8];
        } Bp;
        struct { float sv[256 * 5]; int si[256 * 5]; int cmS; } Dp;
    } u;

    if (blockIdx.x < ABLK_) {
        // ================= kB part =================
        int blk = blockIdx.x;
        if (tid < G_ * 5) u.Bp.tr[tid] = targets[b * G_ * 5 + tid];
        if (tid < G_) u.Bp.hist[tid] = 0;
        {   // match_cnt: 8 threads per g, each sums 8 of the 64 blk counts (coalesced)
            int g8 = tid >> 3, l8 = tid & 7;
            int s = 0;
#pragma unroll
            for (int j = 0; j < 8; ++j)
                s += histA[(l8 * 8 + j) * 256 + b * G_ + g8];
            s += __shfl_down(s, 4, 8);
            s += __shfl_down(s, 2, 8);
            s += __shfl_down(s, 1, 8);
            if (l8 == 0) u.Bp.outf[g8] = (s < K_) ? 1 : 0;
        }
        __syncthreads();
        if (tid < G_)
            u.Bp.gA[tid] = (u.Bp.tr[tid * 5 + 2] - u.Bp.tr[tid * 5 + 0]) *
                           (u.Bp.tr[tid * 5 + 3] - u.Bp.tr[tid * 5 + 1]);
        __syncthreads();

        double fl = 0.0, sl = 0.0;
#pragma unroll
        for (int j = 0; j < 4; ++j) {
            int p = blk * APB_ + j * 256 + tid;
            float4 pr = ((const float4*)priors)[p];
            float4 lc = ((const float4*)loc)[(size_t)b * P_ + p];
            float bs = best_score[b * P_ + p];
            int bi = best_idx[b * P_ + p];
            DecBox d = decode_box(pr, lc);
            bool n_pos = bs > T1_;
            float cmax = -INFINITY, mbest = -INFINITY;
            int mg = 0;
            for (int g = 0; g < G_; ++g) {
                float v = iou_dec(d, u.Bp.gA[g], u.Bp.tr[g * 5], u.Bp.tr[g * 5 + 1],
                                  u.Bp.tr[g * 5 + 2], u.Bp.tr[g * 5 + 3]);
                cmax = fmaxf(cmax, v);
                bool kill = u.Bp.outf[g] && (bi == g) && n_pos;
                float v2 = kill ? 0.f : v;
                float m = u.Bp.outf[g] ? v2 : -1.f;
                if (m > mbest) { mbest = m; mg = g; }  // first-max
            }
            if (mbest > T2_) atomicAdd(&u.Bp.hist[mg], 1);  // LDS atomic only
            bool ignore = (cmax > T2_) && (bs < T1_);
            bool neg = !(n_pos || ignore);
            int lab = (int)u.Bp.tr[bi * 5 + 4];
            float2 cf = ((const float2*)conf)[(size_t)b * P_ + p];
            float cfs[2] = {cf.x, cf.y};
#pragma unroll
            for (int c = 0; c < C_; ++c) {
                if (n_pos) fl += (double)focal_f((c == lab) ? 1.f : 0.f, cfs[c], 1.f);
                else if (neg) fl += (double)focal_f(0.f, cfs[c], 1.f);
            }
            if (n_pos) {
                float tx1 = u.Bp.tr[bi * 5], ty1 = u.Bp.tr[bi * 5 + 1];
                float tx2 = u.Bp.tr[bi * 5 + 2], ty2 = u.Bp.tr[bi * 5 + 3];
                float e0 = ((tx1 + tx2) * 0.5f - pr.x) / (V0_ * pr.z);
                float e1 = ((ty1 + ty2) * 0.5f - pr.y) / (V0_ * pr.w);
                float e2 = logf((tx2 - tx1) / pr.z) / V1_;
                float e3 = logf((ty2 - ty1) / pr.w) / V1_;
                sl += (double)sml1(lc.x, e0) + (double)sml1(lc.y, e1) +
                      (double)sml1(lc.z, e2) + (double)sml1(lc.w, e3);
            }
        }
        int lane = tid & 63, w = tid >> 6;
        for (int off = 32; off > 0; off >>= 1) {
            fl += __shfl_down(fl, off, 64);
            sl += __shfl_down(sl, off, 64);
        }
        if (lane == 0) { u.Bp.wred[w] = fl; u.Bp.wred[4 + w] = sl; }
        __syncthreads();  // wred + hist final
        if (tid == 0)
            fl_n_p[b * ABLK_ + blk] = u.Bp.wred[0] + u.Bp.wred[1] + u.Bp.wred[2] + u.Bp.wred[3];
        if (tid == 1)
            sl_n_p[b * ABLK_ + blk] = u.Bp.wred[4] + u.Bp.wred[5] + u.Bp.wred[6] + u.Bp.wred[7];
        if (tid < G_) histC[blk * 256 + b * G_ + tid] = u.Bp.hist[tid];
    } else {
        // ================= kD part: full-row top-5, gated on mc<K (rare) ================
        int tg = blockIdx.x - ABLK_, tb = b;
        if (tid < 64) {  // mc = column sum of histA
            int v = histA[tid * 256 + tb * G_ + tg];
            for (int off = 32; off > 0; off >>= 1) v += __shfl_down(v, off, 64);
            if (tid == 0) u.Dp.cmS = v;
        }
        __syncthreads();
        int mc = u.Dp.cmS;
        if (mc >= K_) return;  // uniform per block; almost always exits here

        const float* tgp = targets + (tb * G_ + tg) * 5;
        float tx1 = tgp[0], ty1 = tgp[1], tx2 = tgp[2], ty2 = tgp[3];
        float aa = (tx2 - tx1) * (ty2 - ty1);
        float lv[5];
        int li[5];
#pragma unroll
        for (int k = 0; k < 5; ++k) { lv[k] = -INFINITY; li[k] = 0x7fffffff; }
        for (int it = 0; it < P_ / 256; ++it) {
            int p = it * 256 + tid;
            int pbi = best_idx[tb * P_ + p];
            float pbs = best_score[tb * P_ + p];
            float v2;
            if (pbi == tg && pbs > T1_) v2 = 0.f;  // kill (outface true: mc<K)
            else {
                float4 pr = ((const float4*)priors)[p];
                float4 lc = ((const float4*)loc)[(size_t)tb * P_ + p];
                v2 = iou_dec(decode_box(pr, lc), aa, tx1, ty1, tx2, ty2);
            }
            top5_insert(v2, p, lv, li);
        }
#pragma unroll
        for (int k = 0; k < 5; ++k) { u.Dp.sv[tid * 5 + k] = lv[k]; u.Dp.si[tid * 5 + k] = li[k]; }
        __syncthreads();
        for (int str = 128; str > 0; str >>= 1) {
            if (tid < str) {
                int a = 0, c = 0;
                float ov[5];
                int oi[5];
#pragma unroll
                for (int k = 0; k < 5; ++k) {
                    float va = u.Dp.sv[tid * 5 + a], vb = u.Dp.sv[(tid + str) * 5 + c];
                    int ia = u.Dp.si[tid * 5 + a], ib = u.Dp.si[(tid + str) * 5 + c];
                    bool ta = (va > vb) || (va == vb && ia < ib);
                    ov[k] = ta ? va : vb;
                    oi[k] = ta ? ia : ib;
                    if (ta) a++; else c++;
                }
#pragma unroll
                for (int k = 0; k < 5; ++k) { u.Dp.sv[tid * 5 + k] = ov[k]; u.Dp.si[tid * 5 + k] = oi[k]; }
            }
            __syncthreads();
        }
        if (tid == 0) {
#pragma unroll
            for (int k = 0; k < 5; ++k) {
                cv5[(tb * G_ + tg) * 5 + k] = u.Dp.sv[k];
                ci5[(tb * G_ + tg) * 5 + k] = u.Dp.si[k];
            }
        }
    }
}

// ---------------- kTail: mc/cm sums, override resolution, comp losses, finalize --------
__global__ __launch_bounds__(256) void kTail(
    const float* __restrict__ loc, const float* __restrict__ conf,
    const float* __restrict__ priors, const float* __restrict__ targets,
    const int* __restrict__ histA, const int* __restrict__ histC,
    const double* __restrict__ fl_n_p, const double* __restrict__ sl_n_p,
    const float* __restrict__ cv5, const int* __restrict__ ci5,
    float* __restrict__ out) {
    int t = threadIdx.x, b = t >> 5, g = t & 31;
    __shared__ int selp[256][5];
    __shared__ int nS[256];
    __shared__ double aFlc[B_], aSlc[B_], aFln[B_], aSln[B_];
    __shared__ int aNp[B_], aCs[B_], aNpc[B_];

    // mc/cm: 64 coalesced column-sum iterations each
    int mc = 0, cm = 0;
#pragma unroll 8
    for (int blk = 0; blk < ABLK_; ++blk) {
        mc += histA[blk * 256 + t];
        cm += histC[blk * 256 + t];
    }
    int n = (mc < K_) ? min(cm, K_ - mc) : 0;
    nS[t] = n;
    float mv[5];
    int mi[5];
#pragma unroll
    for (int k = 0; k < 5; ++k) {
        mv[k] = (n > 0) ? cv5[t * 5 + k] : -INFINITY;  // kD wrote this row iff mc<K
        mi[k] = (n > 0) ? ci5[t * 5 + k] : 0x7fffffff;
        selp[t][k] = (k < n) ? mi[k] : -1;
    }
    __syncthreads();

    // override resolution (ascending g: later g wins) + compensation losses
    double flc = 0.0, slc = 0.0;
    int alive = 0;
    float tg0 = targets[t * 5 + 0], tg1 = targets[t * 5 + 1];
    float tg2 = targets[t * 5 + 2], tg3 = targets[t * 5 + 3];
    float labf = targets[t * 5 + 4];
    int labi = (int)labf;
    for (int k = 0; k < n; ++k) {
        int p = mi[k];
        bool dead = false;
        for (int g2 = g + 1; g2 < G_; ++g2) {
            int q = b * G_ + g2;
            int n2 = nS[q];
            for (int k2 = 0; k2 < n2; ++k2)
                if (selp[q][k2] == p) dead = true;
        }
        if (!dead) {
            alive++;
            float4 pr = ((const float4*)priors)[p];
            float4 lc = ((const float4*)loc)[(size_t)b * P_ + p];
            float e0 = ((tg0 + tg2) * 0.5f - pr.x) / (V0_ * pr.z);
            float e1 = ((tg1 + tg3) * 0.5f - pr.y) / (V0_ * pr.w);
            float e2 = logf((tg2 - tg0) / pr.z) / V1_;
            float e3 = logf((tg3 - tg1) / pr.w) / V1_;
            slc += (double)sml1(lc.x, e0) + (double)sml1(lc.y, e1) +
                   (double)sml1(lc.z, e2) + (double)sml1(lc.w, e3);
            float2 cf = ((const float2*)conf)[(size_t)b * P_ + p];
            float cfs[2] = {cf.x, cf.y};
#pragma unroll
            for (int c = 0; c < C_; ++c) {
                float tt = (c == labi) ? labf : 0.f;  // labels[g] * one_hot
                flc += (double)focal_f(tt, cfs[c], mv[k]);
            }
        }
    }

    // per-b reductions within 32-thread subgroups (64 partial slots per image)
    int rmc = mc, rn = n, ra = alive;
    double rf = flc, rs = slc;
    double pf = 0.0, ps = 0.0;
#pragma unroll
    for (int j = 0; j < 2; ++j) {
        pf += fl_n_p[b * ABLK_ + g * 2 + j];
        ps += sl_n_p[b * ABLK_ + g * 2 + j];
    }
    for (int off = 16; off > 0; off >>= 1) {
        rmc += __shfl_down(rmc, off, 32);
        rn += __shfl_down(rn, off, 32);
        ra += __shfl_down(ra, off, 32);
        rf += __shfl_down(rf, off, 32);
        rs += __shfl_down(rs, off, 32);
        pf += __shfl_down(pf, off, 32);
        ps += __shfl_down(ps, off, 32);
    }
    if (g == 0) {
        aNp[b] = rmc; aCs[b] = rn; aNpc[b] = ra;
        aFlc[b] = rf; aSlc[b] = rs; aFln[b] = pf; aSln[b] = ps;
    }
    __syncthreads();
    if (t == 0) {
        double sll = 0.0, scl = 0.0;
        for (int b2 = 0; b2 < B_; ++b2) {
            double l_loc = 0.0, l_cls = 0.0;
            int npos = aNp[b2];
            if (npos > 0) {
                l_cls += aFln[b2] / (double)npos;
                l_loc += aSln[b2] / (double)npos;
            }
            int csum = aCs[b2];
            if (csum > 0) {
                int npc = (aNpc[b2] > 1) ? aNpc[b2] : 1;
                l_loc += aSlc[b2] / (double)npc;
                l_cls += aFlc[b2] / (double)csum;
            }
            sll += l_loc;
            scl += l_cls;
        }
        out[0] = (float)(sll / B_);
        out[1] = (float)(scl / B_);
    }
}

extern "C" void kernel_launch(void* const* d_in, const int* in_sizes, int n_in,
                              void* d_out, int out_size, void* d_ws, size_t ws_size,
                              hipStream_t stream) {
    (void)in_sizes; (void)n_in; (void)out_size; (void)ws_size;
    const float* loc = (const float*)d_in[0];
    const float* conf = (const float*)d_in[1];
    const float* priors = (const float*)d_in[2];
    const float* targets = (const float*)d_in[3];
    float* out = (float*)d_out;
    char* ws = (char*)d_ws;

    float* best_score = (float*)ws;                               // 2 MB
    int* best_idx = (int*)(ws + (size_t)2 * 1024 * 1024);         // 2 MB
    double* fl_n_p = (double*)(ws + (size_t)4 * 1024 * 1024);     // 512 doubles
    double* sl_n_p = fl_n_p + B_ * ABLK_;                         // 512 doubles
    float* cv5 = (float*)(sl_n_p + B_ * ABLK_);                   // 1280 floats
    int* ci5 = (int*)(cv5 + B_ * G_ * 5);                         // 1280 ints
    int* histA = ci5 + B_ * G_ * 5;                               // 16K ints
    int* histC = histA + ABLK_ * 256;                             // 16K ints

    kA<<<dim3(ABLK_, B_), 256, 0, stream>>>(priors, targets, best_score, best_idx, histA);
    kBD<<<dim3(ABLK_ + G_, B_), 256, 0, stream>>>(loc, conf, priors, targets,
                                                  best_score, best_idx, histA,
                                                  histC, fl_n_p, sl_n_p, cv5, ci5);
    kTail<<<1, 256, 0, stream>>>(loc, conf, priors, targets, histA, histC,
                                 fl_n_p, sl_n_p, cv5, ci5, out);
}

// Round 12
// 59.376 us; speedup vs baseline: 1.0840x; 1.0055x over previous
//
#include <hip/hip_runtime.h>

#define B_ 8
#define P_ 65536
#define G_ 32
#define C_ 2
#define K_ 5
#define T1_ 0.35f
#define T2_ 0.5f
#define ALPHA_ 0.25f
#define BETA_ 0.11f
#define V0_ 0.1f
#define V1_ 0.2f

#define ABLK_ 64                  // kA / kB-part blocks per image (4 anchors/thread)
#define APB_ 1024                 // anchors per block

// ws layout (plain-store scratch; every word written each call before any read):
//   [0)      float  best_score[B_*P_]        2 MB
//   +2MB     int    best_idx[B_*P_]          2 MB
//   +4MB     double fl_n_p[512]; sl_n_p[512]            8 KB
//   +..      float  cv5[256*5]; int ci5[256*5]          10 KB
//   +..      int    histA[64][256]; histC[64][256]      128 KB   ([blk][b*32+g])

// ---------------- numerics helpers (contract off => deterministic across call sites) ----
struct DecBox { float x1, y1, x2, y2, area; };

__device__ __forceinline__ DecBox decode_box(float4 pr, float4 lc) {
#pragma clang fp contract(off)
    DecBox d;
    float dcx = pr.x + lc.x * V0_ * pr.z;
    float dcy = pr.y + lc.y * V0_ * pr.w;
    float dw = pr.z * expf(lc.z * V1_);
    float dh = pr.w * expf(lc.w * V1_);
    d.x1 = dcx - dw * 0.5f; d.y1 = dcy - dh * 0.5f;
    d.x2 = dcx + dw * 0.5f; d.y2 = dcy + dh * 0.5f;
    d.area = (d.x2 - d.x1) * (d.y2 - d.y1);
    return d;
}

__device__ __forceinline__ float iou_dec(DecBox d, float aa,
                                         float tx1, float ty1, float tx2, float ty2) {
#pragma clang fp contract(off)
    float lx = fmaxf(tx1, d.x1), ly = fmaxf(ty1, d.y1);
    float rx = fminf(tx2, d.x2), ry = fminf(ty2, d.y2);
    float w = fmaxf(rx - lx, 0.f), hh = fmaxf(ry - ly, 0.f);
    float inter = w * hh;
    return inter / (aa + d.area - inter);
}

__device__ __forceinline__ float focal_f(float t, float x, float fiou) {
    float ce = fmaxf(x, 0.f) - x * t + log1pf(expf(-fabsf(x)));
    float a = (t * ALPHA_ + (1.f - t) * (1.f - ALPHA_)) * fiou;
    float pt = (t == 1.0f) ? x : 1.f - x;
    float om = 1.f - pt;
    return a * om * om * ce;  // GAMMA = 2
}

__device__ __forceinline__ float sml1(float p, float t) {
    float x = fabsf(p - t);
    return (x >= BETA_) ? (x - 0.5f * BETA_) : (0.5f * x * x / BETA_);
}

// top-5 by (value desc, index asc) — the stable-argsort order
__device__ __forceinline__ void top5_insert(float v, int i, float lv[5], int li[5]) {
    if ((v > lv[4]) || (v == lv[4] && i < li[4])) {
        lv[4] = v; li[4] = i;
#pragma unroll
        for (int k = 4; k > 0; --k) {
            bool sw = (lv[k] > lv[k - 1]) || (lv[k] == lv[k - 1] && li[k] < li[k - 1]);
            if (sw) {
                float tv = lv[k]; lv[k] = lv[k - 1]; lv[k - 1] = tv;
                int ti = li[k]; li[k] = li[k - 1]; li[k - 1] = ti;
            }
        }
    }
}

// ---------------- kA: best match per anchor; per-block hist (coalesced plain stores) ----
__global__ __launch_bounds__(256) void kA(const float* __restrict__ priors,
                                          const float* __restrict__ targets,
                                          float* __restrict__ best_score,
                                          int* __restrict__ best_idx,
                                          int* __restrict__ histA) {
    int tid = threadIdx.x, blk = blockIdx.x, b = blockIdx.y;
    __shared__ float tr[G_ * 5];
    __shared__ float gA[G_];
    __shared__ int hist[G_];
    if (tid < G_ * 5) tr[tid] = targets[b * G_ * 5 + tid];
    if (tid < G_) hist[tid] = 0;
    __syncthreads();
    if (tid < G_)
        gA[tid] = (tr[tid * 5 + 2] - tr[tid * 5 + 0]) * (tr[tid * 5 + 3] - tr[tid * 5 + 1]);
    __syncthreads();
#pragma unroll
    for (int j = 0; j < 4; ++j) {
        int p = blk * APB_ + j * 256 + tid;
        float4 pr = ((const float4*)priors)[p];
        float px1 = pr.x - pr.z * 0.5f, py1 = pr.y - pr.w * 0.5f;
        float px2 = pr.x + pr.z * 0.5f, py2 = pr.y + pr.w * 0.5f;
        float parea = (px2 - px1) * (py2 - py1);
        float best = -INFINITY;
        int bix = 0;
        for (int g = 0; g < G_; ++g) {
            float lx = fmaxf(tr[g * 5 + 0], px1), ly = fmaxf(tr[g * 5 + 1], py1);
            float rx = fminf(tr[g * 5 + 2], px2), ry = fminf(tr[g * 5 + 3], py2);
            float w = fmaxf(rx - lx, 0.f), hh = fmaxf(ry - ly, 0.f);
            float inter = w * hh;
            float v = inter / (gA[g] + parea - inter);
            if (v > best) { best = v; bix = g; }  // first-max == jnp.argmax
        }
        best_score[b * P_ + p] = best;
        best_idx[b * P_ + p] = bix;
        if (best > T1_) atomicAdd(&hist[bix], 1);  // LDS atomic only
    }
    __syncthreads();
    if (tid < G_) histA[blk * 256 + b * G_ + tid] = hist[tid];
}

// ---------------- kBD: heterogeneous. x<64: kB (losses + histC). x>=64: kD top-5 -------
__global__ __launch_bounds__(256) void kBD(
    const float* __restrict__ loc, const float* __restrict__ conf,
    const float* __restrict__ priors, const float* __restrict__ targets,
    const float* __restrict__ best_score, const int* __restrict__ best_idx,
    const int* __restrict__ histA,
    int* __restrict__ histC,
    double* __restrict__ fl_n_p, double* __restrict__ sl_n_p,
    float* __restrict__ cv5, int* __restrict__ ci5) {
    int tid = threadIdx.x, b = blockIdx.y;
    __shared__ union USm {
        struct {
            float tr[G_ * 5]; float gA[G_];
            int outf[G_]; int hist[G_]; double wred[8];
        } Bp;
        struct { float sv[256 * 5]; int si[256 * 5]; int cmS; } Dp;
    } u;

    if (blockIdx.x < ABLK_) {
        // ================= kB part =================
        int blk = blockIdx.x;
        if (tid < G_ * 5) u.Bp.tr[tid] = targets[b * G_ * 5 + tid];
        if (tid < G_) u.Bp.hist[tid] = 0;
        {   // match_cnt: 8 threads per g, each sums 8 of the 64 blk counts (coalesced)
            int g8 = tid >> 3, l8 = tid & 7;
            int s = 0;
#pragma unroll
            for (int j = 0; j < 8; ++j)
                s += histA[(l8 * 8 + j) * 256 + b * G_ + g8];
            s += __shfl_down(s, 4, 8);
            s += __shfl_down(s, 2, 8);
            s += __shfl_down(s, 1, 8);
            if (l8 == 0) u.Bp.outf[g8] = (s < K_) ? 1 : 0;
        }
        __syncthreads();
        if (tid < G_)
            u.Bp.gA[tid] = (u.Bp.tr[tid * 5 + 2] - u.Bp.tr[tid * 5 + 0]) *
                           (u.Bp.tr[tid * 5 + 3] - u.Bp.tr[tid * 5 + 1]);
        __syncthreads();

        double fl = 0.0, sl = 0.0;
#pragma unroll
        for (int j = 0; j < 4; ++j) {
            int p = blk * APB_ + j * 256 + tid;
            float4 pr = ((const float4*)priors)[p];
            float4 lc = ((const float4*)loc)[(size_t)b * P_ + p];
            float bs = best_score[b * P_ + p];
            int bi = best_idx[b * P_ + p];
            DecBox d = decode_box(pr, lc);
            bool n_pos = bs > T1_;
            float cmax = -INFINITY, mbest = -INFINITY;
            int mg = 0;
            for (int g = 0; g < G_; ++g) {
                float v = iou_dec(d, u.Bp.gA[g], u.Bp.tr[g * 5], u.Bp.tr[g * 5 + 1],
                                  u.Bp.tr[g * 5 + 2], u.Bp.tr[g * 5 + 3]);
                cmax = fmaxf(cmax, v);
                bool kill = u.Bp.outf[g] && (bi == g) && n_pos;
                float v2 = kill ? 0.f : v;
                float m = u.Bp.outf[g] ? v2 : -1.f;
                if (m > mbest) { mbest = m; mg = g; }  // first-max
            }
            if (mbest > T2_) atomicAdd(&u.Bp.hist[mg], 1);  // LDS atomic only
            bool ignore = (cmax > T2_) && (bs < T1_);
            bool neg = !(n_pos || ignore);
            int lab = (int)u.Bp.tr[bi * 5 + 4];
            float2 cf = ((const float2*)conf)[(size_t)b * P_ + p];
            float cfs[2] = {cf.x, cf.y};
#pragma unroll
            for (int c = 0; c < C_; ++c) {
                if (n_pos) fl += (double)focal_f((c == lab) ? 1.f : 0.f, cfs[c], 1.f);
                else if (neg) fl += (double)focal_f(0.f, cfs[c], 1.f);
            }
            if (n_pos) {
                float tx1 = u.Bp.tr[bi * 5], ty1 = u.Bp.tr[bi * 5 + 1];
                float tx2 = u.Bp.tr[bi * 5 + 2], ty2 = u.Bp.tr[bi * 5 + 3];
                float e0 = ((tx1 + tx2) * 0.5f - pr.x) / (V0_ * pr.z);
                float e1 = ((ty1 + ty2) * 0.5f - pr.y) / (V0_ * pr.w);
                float e2 = logf((tx2 - tx1) / pr.z) / V1_;
                float e3 = logf((ty2 - ty1) / pr.w) / V1_;
                sl += (double)sml1(lc.x, e0) + (double)sml1(lc.y, e1) +
                      (double)sml1(lc.z, e2) + (double)sml1(lc.w, e3);
            }
        }
        int lane = tid & 63, w = tid >> 6;
        for (int off = 32; off > 0; off >>= 1) {
            fl += __shfl_down(fl, off, 64);
            sl += __shfl_down(sl, off, 64);
        }
        if (lane == 0) { u.Bp.wred[w] = fl; u.Bp.wred[4 + w] = sl; }
        __syncthreads();  // wred + hist final
        if (tid == 0)
            fl_n_p[b * ABLK_ + blk] = u.Bp.wred[0] + u.Bp.wred[1] + u.Bp.wred[2] + u.Bp.wred[3];
        if (tid == 1)
            sl_n_p[b * ABLK_ + blk] = u.Bp.wred[4] + u.Bp.wred[5] + u.Bp.wred[6] + u.Bp.wred[7];
        if (tid < G_) histC[blk * 256 + b * G_ + tid] = u.Bp.hist[tid];
    } else {
        // ================= kD part: full-row top-5, gated on mc<K (rare) ================
        int tg = blockIdx.x - ABLK_, tb = b;
        if (tid < 64) {  // mc = column sum of histA
            int v = histA[tid * 256 + tb * G_ + tg];
            for (int off = 32; off > 0; off >>= 1) v += __shfl_down(v, off, 64);
            if (tid == 0) u.Dp.cmS = v;
        }
        __syncthreads();
        int mc = u.Dp.cmS;
        if (mc >= K_) return;  // uniform per block; almost always exits here

        const float* tgp = targets + (tb * G_ + tg) * 5;
        float tx1 = tgp[0], ty1 = tgp[1], tx2 = tgp[2], ty2 = tgp[3];
        float aa = (tx2 - tx1) * (ty2 - ty1);
        float lv[5];
        int li[5];
#pragma unroll
        for (int k = 0; k < 5; ++k) { lv[k] = -INFINITY; li[k] = 0x7fffffff; }
        for (int it = 0; it < P_ / 256; ++it) {
            int p = it * 256 + tid;
            int pbi = best_idx[tb * P_ + p];
            float pbs = best_score[tb * P_ + p];
            float v2;
            if (pbi == tg && pbs > T1_) v2 = 0.f;  // kill (outface true: mc<K)
            else {
                float4 pr = ((const float4*)priors)[p];
                float4 lc = ((const float4*)loc)[(size_t)tb * P_ + p];
                v2 = iou_dec(decode_box(pr, lc), aa, tx1, ty1, tx2, ty2);
            }
            top5_insert(v2, p, lv, li);
        }
#pragma unroll
        for (int k = 0; k < 5; ++k) { u.Dp.sv[tid * 5 + k] = lv[k]; u.Dp.si[tid * 5 + k] = li[k]; }
        __syncthreads();
        for (int str = 128; str > 0; str >>= 1) {
            if (tid < str) {
                int a = 0, c = 0;
                float ov[5];
                int oi[5];
#pragma unroll
                for (int k = 0; k < 5; ++k) {
                    float va = u.Dp.sv[tid * 5 + a], vb = u.Dp.sv[(tid + str) * 5 + c];
                    int ia = u.Dp.si[tid * 5 + a], ib = u.Dp.si[(tid + str) * 5 + c];
                    bool ta = (va > vb) || (va == vb && ia < ib);
                    ov[k] = ta ? va : vb;
                    oi[k] = ta ? ia : ib;
                    if (ta) a++; else c++;
                }
#pragma unroll
                for (int k = 0; k < 5; ++k) { u.Dp.sv[tid * 5 + k] = ov[k]; u.Dp.si[tid * 5 + k] = oi[k]; }
            }
            __syncthreads();
        }
        if (tid == 0) {
#pragma unroll
            for (int k = 0; k < 5; ++k) {
                cv5[(tb * G_ + tg) * 5 + k] = u.Dp.sv[k];
                ci5[(tb * G_ + tg) * 5 + k] = u.Dp.si[k];
            }
        }
    }
}

// ---------------- kTail: mc/cm sums, override resolution, comp losses, finalize --------
__global__ __launch_bounds__(256) void kTail(
    const float* __restrict__ loc, const float* __restrict__ conf,
    const float* __restrict__ priors, const float* __restrict__ targets,
    const int* __restrict__ histA, const int* __restrict__ histC,
    const double* __restrict__ fl_n_p, const double* __restrict__ sl_n_p,
    const float* __restrict__ cv5, const int* __restrict__ ci5,
    float* __restrict__ out) {
    int t = threadIdx.x, b = t >> 5, g = t & 31;
    __shared__ int selp[256][5];
    __shared__ int nS[256];
    __shared__ double aFlc[B_], aSlc[B_], aFln[B_], aSln[B_];
    __shared__ int aNp[B_], aCs[B_], aNpc[B_];

    // mc/cm: 64 coalesced column-sum iterations each
    int mc = 0, cm = 0;
#pragma unroll 8
    for (int blk = 0; blk < ABLK_; ++blk) {
        mc += histA[blk * 256 + t];
        cm += histC[blk * 256 + t];
    }
    int n = (mc < K_) ? min(cm, K_ - mc) : 0;
    nS[t] = n;
    float mv[5];
    int mi[5];
#pragma unroll
    for (int k = 0; k < 5; ++k) {
        mv[k] = (n > 0) ? cv5[t * 5 + k] : -INFINITY;  // kD wrote this row iff mc<K
        mi[k] = (n > 0) ? ci5[t * 5 + k] : 0x7fffffff;
        selp[t][k] = (k < n) ? mi[k] : -1;
    }
    __syncthreads();

    // override resolution (ascending g: later g wins) + compensation losses
    double flc = 0.0, slc = 0.0;
    int alive = 0;
    float tg0 = targets[t * 5 + 0], tg1 = targets[t * 5 + 1];
    float tg2 = targets[t * 5 + 2], tg3 = targets[t * 5 + 3];
    float labf = targets[t * 5 + 4];
    int labi = (int)labf;
    for (int k = 0; k < n; ++k) {
        int p = mi[k];
        bool dead = false;
        for (int g2 = g + 1; g2 < G_; ++g2) {
            int q = b * G_ + g2;
            int n2 = nS[q];
            for (int k2 = 0; k2 < n2; ++k2)
                if (selp[q][k2] == p) dead = true;
        }
        if (!dead) {
            alive++;
            float4 pr = ((const float4*)priors)[p];
            float4 lc = ((const float4*)loc)[(size_t)b * P_ + p];
            float e0 = ((tg0 + tg2) * 0.5f - pr.x) / (V0_ * pr.z);
            float e1 = ((tg1 + tg3) * 0.5f - pr.y) / (V0_ * pr.w);
            float e2 = logf((tg2 - tg0) / pr.z) / V1_;
            float e3 = logf((tg3 - tg1) / pr.w) / V1_;
            slc += (double)sml1(lc.x, e0) + (double)sml1(lc.y, e1) +
                   (double)sml1(lc.z, e2) + (double)sml1(lc.w, e3);
            float2 cf = ((const float2*)conf)[(size_t)b * P_ + p];
            float cfs[2] = {cf.x, cf.y};
#pragma unroll
            for (int c = 0; c < C_; ++c) {
                float tt = (c == labi) ? labf : 0.f;  // labels[g] * one_hot
                flc += (double)focal_f(tt, cfs[c], mv[k]);
            }
        }
    }

    // per-b reductions within 32-thread subgroups (64 partial slots per image)
    int rmc = mc, rn = n, ra = alive;
    double rf = flc, rs = slc;
    double pf = 0.0, ps = 0.0;
#pragma unroll
    for (int j = 0; j < 2; ++j) {
        pf += fl_n_p[b * ABLK_ + g * 2 + j];
        ps += sl_n_p[b * ABLK_ + g * 2 + j];
    }
    for (int off = 16; off > 0; off >>= 1) {
        rmc += __shfl_down(rmc, off, 32);
        rn += __shfl_down(rn, off, 32);
        ra += __shfl_down(ra, off, 32);
        rf += __shfl_down(rf, off, 32);
        rs += __shfl_down(rs, off, 32);
        pf += __shfl_down(pf, off, 32);
        ps += __shfl_down(ps, off, 32);
    }
    if (g == 0) {
        aNp[b] = rmc; aCs[b] = rn; aNpc[b] = ra;
        aFlc[b] = rf; aSlc[b] = rs; aFln[b] = pf; aSln[b] = ps;
    }
    __syncthreads();
    if (t == 0) {
        double sll = 0.0, scl = 0.0;
        for (int b2 = 0; b2 < B_; ++b2) {
            double l_loc = 0.0, l_cls = 0.0;
            int npos = aNp[b2];
            if (npos > 0) {
                l_cls += aFln[b2] / (double)npos;
                l_loc += aSln[b2] / (double)npos;
            }
            int csum = aCs[b2];
            if (csum > 0) {
                int npc = (aNpc[b2] > 1) ? aNpc[b2] : 1;
                l_loc += aSlc[b2] / (double)npc;
                l_cls += aFlc[b2] / (double)csum;
            }
            sll += l_loc;
            scl += l_cls;
        }
        out[0] = (float)(sll / B_);
        out[1] = (float)(scl / B_);
    }
}

extern "C" void kernel_launch(void* const* d_in, const int* in_sizes, int n_in,
                              void* d_out, int out_size, void* d_ws, size_t ws_size,
                              hipStream_t stream) {
    (void)in_sizes; (void)n_in; (void)out_size; (void)ws_size;
    const float* loc = (const float*)d_in[0];
    const float* conf = (const float*)d_in[1];
    const float* priors = (const float*)d_in[2];
    const float* targets = (const float*)d_in[3];
    float* out = (float*)d_out;
    char* ws = (char*)d_ws;

    float* best_score = (float*)ws;                               // 2 MB
    int* best_idx = (int*)(ws + (size_t)2 * 1024 * 1024);         // 2 MB
    double* fl_n_p = (double*)(ws + (size_t)4 * 1024 * 1024);     // 512 doubles
    double* sl_n_p = fl_n_p + B_ * ABLK_;                         // 512 doubles
    float* cv5 = (float*)(sl_n_p + B_ * ABLK_);                   // 1280 floats
    int* ci5 = (int*)(cv5 + B_ * G_ * 5);                         // 1280 ints
    int* histA = ci5 + B_ * G_ * 5;                               // 16K ints
    int* histC = histA + ABLK_ * 256;                             // 16K ints

    kA<<<dim3(ABLK_, B_), 256, 0, stream>>>(priors, targets, best_score, best_idx, histA);
    kBD<<<dim3(ABLK_ + G_, B_), 256, 0, stream>>>(loc, conf, priors, targets,
                                                  best_score, best_idx, histA,
                                                  histC, fl_n_p, sl_n_p, cv5, ci5);
    kTail<<<1, 256, 0, stream>>>(loc, conf, priors, targets, histA, histC,
                                 fl_n_p, sl_n_p, cv5, ci5, out);
}